// Round 5
// baseline (289.529 us; speedup 1.0000x reference)
//
#include <hip/hip_runtime.h>
#include <hip/hip_bf16.h>
#include <stdint.h>

typedef unsigned short u16;
typedef __attribute__((ext_vector_type(8))) short short8;
typedef __attribute__((ext_vector_type(4))) float f32x4;

// ---------- helpers ----------
__device__ __forceinline__ u16 f2bf(float f) {
    union { float f; uint32_t u; } c; c.f = f;
    uint32_t u = c.u;
    u += 0x7fffu + ((u >> 16) & 1u);   // round-to-nearest-even
    return (u16)(u >> 16);
}

__device__ __forceinline__ void glds16(const void* g, void* l) {
    __builtin_amdgcn_global_load_lds(
        (const __attribute__((address_space(1))) uint32_t*)g,
        (__attribute__((address_space(3))) uint32_t*)l,
        16, 0, 0);
}

// ---------- kernel 1: g_p = FWHT_1024(D_p[:1024] * V) / 1024, for 4 params ----------
__global__ void fwht_g_kernel(const float* __restrict__ V,
                              const float* __restrict__ D0, const float* __restrict__ D1,
                              const float* __restrict__ D2, const float* __restrict__ D3,
                              float* __restrict__ g) {
    __shared__ float s[1024];
    int t = threadIdx.x;
    const float* D = (blockIdx.x == 0) ? D0 : (blockIdx.x == 1) ? D1 :
                     (blockIdx.x == 2) ? D2 : D3;
    s[t] = D[t] * V[t];
    __syncthreads();
    #pragma unroll
    for (int st = 512; st >= 1; st >>= 1) {
        float a = s[t];
        float b = s[t ^ st];
        __syncthreads();
        s[t] = (t & st) ? (b - a) : (a + b);
        __syncthreads();
    }
    g[blockIdx.x * 1024 + t] = s[t] * (1.0f / 1024.0f);
}

// ---------- kernel 2: bias = init + PP * g[i&1023] ----------
__global__ void bias_kernel(const float* __restrict__ init, const float* __restrict__ PP,
                            const float* __restrict__ g, float* __restrict__ out, int n) {
    int i = blockIdx.x * blockDim.x + threadIdx.x;
    if (i < n) out[i] = init[i] + PP[i] * g[i & 1023];
}

// ---------- kernel 3: f32 -> bf16 cast (x), 4 elems/thread ----------
__global__ void cast_kernel(const float* __restrict__ in, u16* __restrict__ out, int n4) {
    int i = blockIdx.x * blockDim.x + threadIdx.x;
    if (i >= n4) return;
    float4 v = ((const float4*)in)[i];
    uint32_t lo = (uint32_t)f2bf(v.x) | ((uint32_t)f2bf(v.y) << 16);
    uint32_t hi = (uint32_t)f2bf(v.z) | ((uint32_t)f2bf(v.w) << 16);
    ((uint2*)out)[i] = make_uint2(lo, hi);
}

// ---------- kernel 4: fused W-gen + split-K GEMM, v2 ----------
// P[sk] = A(256-row slice x Ks) @ W^T, W[n][k] = bf16(Winit + PP * g[k&1023]) generated
// in-register (T14 prefetch one K-step ahead) and ds_written to LDS.
// BM=256, BN=64, BK=64; 256 thr = 4 waves stacked in M; wave tile 64x64, acc[4][4].
// Grid (N/64, M/256, S) = 512 WGs, 40KB LDS -> 3 WG/CU.
__global__ __launch_bounds__(256, 3) void gemm_fused(const u16* __restrict__ A,
                                                     const float* __restrict__ Winit,
                                                     const float* __restrict__ PP,
                                                     const float* __restrict__ gvec,
                                                     float* __restrict__ P,
                                                     int M, int N, int K, int Kslice) {
    constexpr int BM = 256, BN = 64, BK = 64;
    __shared__ u16 As[BM * BK];   // 32 KB
    __shared__ u16 Bs[BN * BK];   // 8 KB

    const int t    = threadIdx.x;
    const int wid  = t >> 6;          // 0..3, owns 64 A-rows
    const int lane = t & 63;
    const int fr   = lane & 15;
    const int fq   = lane >> 4;

    const int bn = blockIdx.x, bm = blockIdx.y, sk = blockIdx.z;
    const int k_beg = sk * Kslice;
    const int nstep = Kslice / BK;

    const u16* Abase = A + (size_t)(bm * BM) * K;

    // B-gen mapping: 64 rows x 64 k f32; thread covers rows rB+{0,16,32,48}, cols cB..cB+3
    const int rB = t >> 4;            // 0..15
    const int cB = (t & 15) * 4;      // 0..60
    const float* Wb = Winit + (size_t)(bn * BN) * K;
    const float* Pb = PP    + (size_t)(bn * BN) * K;

    float4 wi[4], pp[4];              // prefetched W inputs (32 VGPR)

    f32x4 acc[4][4];
    #pragma unroll
    for (int m = 0; m < 4; ++m)
        #pragma unroll
        for (int n = 0; n < 4; ++n)
            acc[m][n] = (f32x4){0.f, 0.f, 0.f, 0.f};

    auto prefetchW = [&](int k0) {
        #pragma unroll
        for (int q = 0; q < 4; ++q) {
            size_t off = (size_t)(rB + q * 16) * K + k0 + cB;
            wi[q] = *(const float4*)(Wb + off);
            pp[q] = *(const float4*)(Pb + off);
        }
    };
    auto writeB = [&](int k0) {
        float4 gv = *(const float4*)(gvec + ((k0 + cB) & 1023));
        #pragma unroll
        for (int q = 0; q < 4; ++q) {
            uint32_t lo = (uint32_t)f2bf(wi[q].x + pp[q].x * gv.x) |
                          ((uint32_t)f2bf(wi[q].y + pp[q].y * gv.y) << 16);
            uint32_t hi = (uint32_t)f2bf(wi[q].z + pp[q].z * gv.z) |
                          ((uint32_t)f2bf(wi[q].w + pp[q].w * gv.w) << 16);
            *(uint2*)(Bs + (rB + q * 16) * BK + cB) = make_uint2(lo, hi);
        }
    };
    auto stageA = [&](int k0) {
        #pragma unroll
        for (int q = 0; q < 8; ++q) {
            int L = q * 256 + t;
            int row = L >> 3;
            int cg  = (L & 7) * 8;
            glds16(Abase + (size_t)row * K + k0 + cg, As + L * 8);
        }
    };

    // prologue: step 0 into LDS
    prefetchW(k_beg);
    stageA(k_beg);
    writeB(k_beg);
    __syncthreads();

    #pragma unroll 1
    for (int s = 0; s < nstep; ++s) {
        const int k0 = k_beg + s * BK;
        const bool nxt = (s + 1 < nstep);
        if (nxt) prefetchW(k0 + BK);          // T14: issue W loads before MFMA phase

        #pragma unroll
        for (int ks = 0; ks < 2; ++ks) {
            short8 a[4], b[4];
            #pragma unroll
            for (int m = 0; m < 4; ++m)
                a[m] = *(const short8*)(As + (wid * 64 + m * 16 + fr) * BK + ks * 32 + fq * 8);
            #pragma unroll
            for (int n = 0; n < 4; ++n)
                b[n] = *(const short8*)(Bs + (n * 16 + fr) * BK + ks * 32 + fq * 8);
            #pragma unroll
            for (int m = 0; m < 4; ++m)
                #pragma unroll
                for (int n = 0; n < 4; ++n)
                    acc[m][n] = __builtin_amdgcn_mfma_f32_16x16x32_bf16(a[m], b[n], acc[m][n], 0, 0, 0);
        }
        __syncthreads();                       // all waves done reading As/Bs
        if (nxt) {
            stageA(k0 + BK);                   // glds A for next step
            writeB(k0 + BK);                   // bf16-gen from prefetched regs
        }
        __syncthreads();                       // drains glds + ds_write
    }

    // epilogue: write f32 partial tile
    float* Pp = P + (size_t)sk * M * N;
    #pragma unroll
    for (int m = 0; m < 4; ++m) {
        int grow0 = bm * BM + wid * 64 + m * 16 + fq * 4;
        #pragma unroll
        for (int n = 0; n < 4; ++n) {
            int gcol = bn * BN + n * 16 + fr;
            #pragma unroll
            for (int j = 0; j < 4; ++j)
                Pp[(size_t)(grow0 + j) * N + gcol] = acc[m][n][j];
        }
    }
}

// ---------- kernel 5: reduce S partials + bias (+relu) -> bf16 or f32 ----------
template <typename OutT, bool RELU, int S>
__global__ void reduce_kernel(const float* __restrict__ P, const float* __restrict__ bias,
                              OutT* __restrict__ out, int MN, int N) {
    int i = blockIdx.x * blockDim.x + threadIdx.x;   // handles 4 elems
    if (i * 4 >= MN) return;
    int e = i * 4;
    int col = e & (N - 1);
    float4 acc = ((const float4*)(P + e))[0];
    #pragma unroll
    for (int s = 1; s < S; ++s) {
        float4 p = ((const float4*)(P + (size_t)s * MN + e))[0];
        acc.x += p.x; acc.y += p.y; acc.z += p.z; acc.w += p.w;
    }
    float4 bv = *((const float4*)(bias + col));
    acc.x += bv.x; acc.y += bv.y; acc.z += bv.z; acc.w += bv.w;
    if (RELU) {
        acc.x = fmaxf(acc.x, 0.f); acc.y = fmaxf(acc.y, 0.f);
        acc.z = fmaxf(acc.z, 0.f); acc.w = fmaxf(acc.w, 0.f);
    }
    if constexpr (sizeof(OutT) == 2) {
        uint32_t lo = (uint32_t)f2bf(acc.x) | ((uint32_t)f2bf(acc.y) << 16);
        uint32_t hi = (uint32_t)f2bf(acc.z) | ((uint32_t)f2bf(acc.w) << 16);
        ((uint2*)out)[i] = make_uint2(lo, hi);
    } else {
        ((float4*)out)[i] = acc;
    }
}

// ---------- launch ----------
extern "C" void kernel_launch(void* const* d_in, const int* in_sizes, int n_in,
                              void* d_out, int out_size, void* d_ws, size_t ws_size,
                              hipStream_t stream) {
    (void)in_sizes; (void)n_in; (void)out_size; (void)ws_size;

    const float* x       = (const float*)d_in[0];
    const float* V       = (const float*)d_in[1];
    const float* W1_init = (const float*)d_in[2];
    const float* D_W1    = (const float*)d_in[3];
    const float* PP_W1   = (const float*)d_in[4];
    const float* b1_init = (const float*)d_in[5];
    const float* D_b1    = (const float*)d_in[6];
    const float* PP_b1   = (const float*)d_in[7];
    const float* W2_init = (const float*)d_in[8];
    const float* D_W2    = (const float*)d_in[9];
    const float* PP_W2   = (const float*)d_in[10];
    const float* b2_init = (const float*)d_in[11];
    const float* D_b2    = (const float*)d_in[12];
    const float* PP_b2   = (const float*)d_in[13];

    constexpr size_t MB = 1024 * 1024;
    char* ws = (char*)d_ws;
    float* g    = (float*)(ws);                      // 4x1024 f32: [W1 | b1 | W2 | b2]
    float* b1w  = (float*)(ws + 16384);              // 4096 f32
    float* b2w  = (float*)(ws + 32768);              // 4096 f32
    u16*   xb   = (u16*)(ws + 65536);                // 512x4096 bf16 (4 MB)
    u16*   hb   = (u16*)(ws + 65536 + 4 * MB);       // 512x4096 bf16 (4 MB)
    float* Pbuf = (float*)(ws + 65536 + 8 * MB);     // 4x512x4096 f32 (32 MB)

    const int M = 512, N = 4096, K = 4096, S = 4, Kslice = K / S;

    fwht_g_kernel<<<4, 1024, 0, stream>>>(V, D_W1, D_b1, D_W2, D_b2, g);
    bias_kernel<<<4, 1024, 0, stream>>>(b1_init, PP_b1, g + 1024, b1w, 4096);
    bias_kernel<<<4, 1024, 0, stream>>>(b2_init, PP_b2, g + 3072, b2w, 4096);
    cast_kernel<<<2048, 256, 0, stream>>>(x, xb, M * K / 4);

    // layer 1: fused W1-gen GEMM
    gemm_fused<<<dim3(N / 64, M / 256, S), 256, 0, stream>>>(xb, W1_init, PP_W1, g, Pbuf, M, N, K, Kslice);
    reduce_kernel<u16, true, S><<<M * N / 4 / 256, 256, 0, stream>>>(Pbuf, b1w, hb, M * N, N);

    // layer 2: fused W2-gen GEMM
    gemm_fused<<<dim3(N / 64, M / 256, S), 256, 0, stream>>>(hb, W2_init, PP_W2, g + 2048, Pbuf, M, N, K, Kslice);
    reduce_kernel<float, false, S><<<M * N / 4 / 256, 256, 0, stream>>>(Pbuf, b2w, (float*)d_out, M * N, N);
}

// Round 6
// 144.608 us; speedup vs baseline: 2.0022x; 2.0022x over previous
//
#include <hip/hip_runtime.h>
#include <hip/hip_bf16.h>
#include <stdint.h>

typedef unsigned short u16;
typedef __attribute__((ext_vector_type(8))) short short8;
typedef __attribute__((ext_vector_type(4))) float f32x4;

// ---------- helpers ----------
__device__ __forceinline__ u16 f2bf(float f) {
    union { float f; uint32_t u; } c; c.f = f;
    uint32_t u = c.u;
    u += 0x7fffu + ((u >> 16) & 1u);   // round-to-nearest-even
    return (u16)(u >> 16);
}

__device__ __forceinline__ void glds16(const void* g, void* l) {
    __builtin_amdgcn_global_load_lds(
        (const __attribute__((address_space(1))) uint32_t*)g,
        (__attribute__((address_space(3))) uint32_t*)l,
        16, 0, 0);
}

// ---------- kernel 1: g_p = FWHT_1024(D_p[:1024] * V) / 1024, for 4 params ----------
__global__ void fwht_g_kernel(const float* __restrict__ V,
                              const float* __restrict__ D0, const float* __restrict__ D1,
                              const float* __restrict__ D2, const float* __restrict__ D3,
                              float* __restrict__ g) {
    __shared__ float s[1024];
    int t = threadIdx.x;
    const float* D = (blockIdx.x == 0) ? D0 : (blockIdx.x == 1) ? D1 :
                     (blockIdx.x == 2) ? D2 : D3;
    s[t] = D[t] * V[t];
    __syncthreads();
    #pragma unroll
    for (int st = 512; st >= 1; st >>= 1) {
        float a = s[t];
        float b = s[t ^ st];
        __syncthreads();
        s[t] = (t & st) ? (b - a) : (a + b);
        __syncthreads();
    }
    g[blockIdx.x * 1024 + t] = s[t] * (1.0f / 1024.0f);
}

// ---------- kernel 2: bias = init + PP * g[i&1023] ----------
__global__ void bias_kernel(const float* __restrict__ init, const float* __restrict__ PP,
                            const float* __restrict__ g, float* __restrict__ out, int n) {
    int i = blockIdx.x * blockDim.x + threadIdx.x;
    if (i < n) out[i] = init[i] + PP[i] * g[i & 1023];
}

// ---------- kernel 3: f32 -> bf16 cast (x), 4 elems/thread ----------
__global__ void cast_kernel(const float* __restrict__ in, u16* __restrict__ out, int n4) {
    int i = blockIdx.x * blockDim.x + threadIdx.x;
    if (i >= n4) return;
    float4 v = ((const float4*)in)[i];
    uint32_t lo = (uint32_t)f2bf(v.x) | ((uint32_t)f2bf(v.y) << 16);
    uint32_t hi = (uint32_t)f2bf(v.z) | ((uint32_t)f2bf(v.w) << 16);
    ((uint2*)out)[i] = make_uint2(lo, hi);
}

// ---------- kernel 4: fused W-gen + split-K GEMM, v3 (spill-free T14) ----------
// P[sk] = A(256-row slice x Ks) @ W^T, W[n][k] = bf16(Winit + PP * g[k&1023]).
// W inputs prefetched into NAMED float4 registers one K-step ahead (no arrays,
// no lambdas -> no scratch), converted + ds_written after the MFMA phase.
// BM=256, BN=64, BK=64; 256 thr = 4 waves stacked in M; wave tile 64x64, acc[4][4].
__global__ __launch_bounds__(256, 2) void gemm_fused(const u16* __restrict__ A,
                                                     const float* __restrict__ Winit,
                                                     const float* __restrict__ PP,
                                                     const float* __restrict__ gvec,
                                                     float* __restrict__ P,
                                                     int M, int N, int K, int Kslice) {
    constexpr int BM = 256, BN = 64, BK = 64;
    __shared__ u16 As[BM * BK];   // 32 KB
    __shared__ u16 Bs[BN * BK];   // 8 KB

    const int t    = threadIdx.x;
    const int wid  = t >> 6;          // 0..3, owns 64 A-rows
    const int lane = t & 63;
    const int fr   = lane & 15;
    const int fq   = lane >> 4;

    const int bn = blockIdx.x, bm = blockIdx.y, sk = blockIdx.z;
    const int k_beg = sk * Kslice;
    const int nstep = Kslice / BK;

    const u16* Abase = A + (size_t)(bm * BM) * K;

    // B-gen mapping: thread covers W rows rB+{0,16,32,48}, k-cols cB..cB+3
    const int rB = t >> 4;            // 0..15
    const int cB = (t & 15) * 4;      // 0..60
    const float* Wb = Winit + (size_t)(bn * BN + rB) * K;
    const float* Pb = PP    + (size_t)(bn * BN + rB) * K;
    const size_t rstride = (size_t)16 * K;

    float4 wi0, wi1, wi2, wi3, pp0, pp1, pp2, pp3;   // named: never spilled

#define PREFETCH_W(k0) do {                                   \
        const float* wp_ = Wb + (k0) + cB;                    \
        const float* qp_ = Pb + (k0) + cB;                    \
        wi0 = *(const float4*)(wp_);                          \
        wi1 = *(const float4*)(wp_ + rstride);                \
        wi2 = *(const float4*)(wp_ + 2 * rstride);            \
        wi3 = *(const float4*)(wp_ + 3 * rstride);            \
        pp0 = *(const float4*)(qp_);                          \
        pp1 = *(const float4*)(qp_ + rstride);                \
        pp2 = *(const float4*)(qp_ + 2 * rstride);            \
        pp3 = *(const float4*)(qp_ + 3 * rstride);            \
    } while (0)

#define WRITE_B(k0) do {                                                          \
        float4 gv_ = *(const float4*)(gvec + (((k0) + cB) & 1023));               \
        uint32_t lo_, hi_;                                                        \
        lo_ = (uint32_t)f2bf(wi0.x + pp0.x * gv_.x) |                             \
              ((uint32_t)f2bf(wi0.y + pp0.y * gv_.y) << 16);                      \
        hi_ = (uint32_t)f2bf(wi0.z + pp0.z * gv_.z) |                             \
              ((uint32_t)f2bf(wi0.w + pp0.w * gv_.w) << 16);                      \
        *(uint2*)(Bs + (rB +  0) * BK + cB) = make_uint2(lo_, hi_);               \
        lo_ = (uint32_t)f2bf(wi1.x + pp1.x * gv_.x) |                             \
              ((uint32_t)f2bf(wi1.y + pp1.y * gv_.y) << 16);                      \
        hi_ = (uint32_t)f2bf(wi1.z + pp1.z * gv_.z) |                             \
              ((uint32_t)f2bf(wi1.w + pp1.w * gv_.w) << 16);                      \
        *(uint2*)(Bs + (rB + 16) * BK + cB) = make_uint2(lo_, hi_);               \
        lo_ = (uint32_t)f2bf(wi2.x + pp2.x * gv_.x) |                             \
              ((uint32_t)f2bf(wi2.y + pp2.y * gv_.y) << 16);                      \
        hi_ = (uint32_t)f2bf(wi2.z + pp2.z * gv_.z) |                             \
              ((uint32_t)f2bf(wi2.w + pp2.w * gv_.w) << 16);                      \
        *(uint2*)(Bs + (rB + 32) * BK + cB) = make_uint2(lo_, hi_);               \
        lo_ = (uint32_t)f2bf(wi3.x + pp3.x * gv_.x) |                             \
              ((uint32_t)f2bf(wi3.y + pp3.y * gv_.y) << 16);                      \
        hi_ = (uint32_t)f2bf(wi3.z + pp3.z * gv_.z) |                             \
              ((uint32_t)f2bf(wi3.w + pp3.w * gv_.w) << 16);                      \
        *(uint2*)(Bs + (rB + 48) * BK + cB) = make_uint2(lo_, hi_);               \
    } while (0)

#define STAGE_A(k0) do {                                                          \
        _Pragma("unroll")                                                         \
        for (int q_ = 0; q_ < 8; ++q_) {                                          \
            int L_ = q_ * 256 + t;                                                \
            int row_ = L_ >> 3;                                                   \
            int cg_ = (L_ & 7) * 8;                                               \
            glds16(Abase + (size_t)row_ * K + (k0) + cg_, As + L_ * 8);           \
        }                                                                         \
    } while (0)

    f32x4 acc[4][4];
    #pragma unroll
    for (int m = 0; m < 4; ++m)
        #pragma unroll
        for (int n = 0; n < 4; ++n)
            acc[m][n] = (f32x4){0.f, 0.f, 0.f, 0.f};

    // prologue: step 0 into LDS
    PREFETCH_W(k_beg);
    STAGE_A(k_beg);
    WRITE_B(k_beg);
    __syncthreads();

    #pragma unroll 1
    for (int s = 0; s < nstep; ++s) {
        const int k0 = k_beg + s * BK;
        const bool nxt = (s + 1 < nstep);
        if (nxt) PREFETCH_W(k0 + BK);          // T14: W loads in flight across MFMA

        #pragma unroll
        for (int ks = 0; ks < 2; ++ks) {
            short8 a[4], b[4];
            #pragma unroll
            for (int m = 0; m < 4; ++m)
                a[m] = *(const short8*)(As + (wid * 64 + m * 16 + fr) * BK + ks * 32 + fq * 8);
            #pragma unroll
            for (int n = 0; n < 4; ++n)
                b[n] = *(const short8*)(Bs + (n * 16 + fr) * BK + ks * 32 + fq * 8);
            #pragma unroll
            for (int m = 0; m < 4; ++m)
                #pragma unroll
                for (int n = 0; n < 4; ++n)
                    acc[m][n] = __builtin_amdgcn_mfma_f32_16x16x32_bf16(a[m], b[n], acc[m][n], 0, 0, 0);
        }
        __syncthreads();                       // all waves done reading As/Bs
        if (nxt) {
            STAGE_A(k0 + BK);                  // glds A for next step
            WRITE_B(k0 + BK);                  // bf16-gen from prefetched named regs
        }
        __syncthreads();                       // drains glds + ds_write
    }

#undef PREFETCH_W
#undef WRITE_B
#undef STAGE_A

    // epilogue: write f32 partial tile
    float* Pp = P + (size_t)sk * M * N;
    #pragma unroll
    for (int m = 0; m < 4; ++m) {
        int grow0 = bm * BM + wid * 64 + m * 16 + fq * 4;
        #pragma unroll
        for (int n = 0; n < 4; ++n) {
            int gcol = bn * BN + n * 16 + fr;
            #pragma unroll
            for (int j = 0; j < 4; ++j)
                Pp[(size_t)(grow0 + j) * N + gcol] = acc[m][n][j];
        }
    }
}

// ---------- kernel 5: reduce S partials + bias (+relu) -> bf16 or f32 ----------
template <typename OutT, bool RELU, int S>
__global__ void reduce_kernel(const float* __restrict__ P, const float* __restrict__ bias,
                              OutT* __restrict__ out, int MN, int N) {
    int i = blockIdx.x * blockDim.x + threadIdx.x;   // handles 4 elems
    if (i * 4 >= MN) return;
    int e = i * 4;
    int col = e & (N - 1);
    float4 acc = ((const float4*)(P + e))[0];
    #pragma unroll
    for (int s = 1; s < S; ++s) {
        float4 p = ((const float4*)(P + (size_t)s * MN + e))[0];
        acc.x += p.x; acc.y += p.y; acc.z += p.z; acc.w += p.w;
    }
    float4 bv = *((const float4*)(bias + col));
    acc.x += bv.x; acc.y += bv.y; acc.z += bv.z; acc.w += bv.w;
    if (RELU) {
        acc.x = fmaxf(acc.x, 0.f); acc.y = fmaxf(acc.y, 0.f);
        acc.z = fmaxf(acc.z, 0.f); acc.w = fmaxf(acc.w, 0.f);
    }
    if constexpr (sizeof(OutT) == 2) {
        uint32_t lo = (uint32_t)f2bf(acc.x) | ((uint32_t)f2bf(acc.y) << 16);
        uint32_t hi = (uint32_t)f2bf(acc.z) | ((uint32_t)f2bf(acc.w) << 16);
        ((uint2*)out)[i] = make_uint2(lo, hi);
    } else {
        ((float4*)out)[i] = acc;
    }
}

// ---------- launch ----------
extern "C" void kernel_launch(void* const* d_in, const int* in_sizes, int n_in,
                              void* d_out, int out_size, void* d_ws, size_t ws_size,
                              hipStream_t stream) {
    (void)in_sizes; (void)n_in; (void)out_size; (void)ws_size;

    const float* x       = (const float*)d_in[0];
    const float* V       = (const float*)d_in[1];
    const float* W1_init = (const float*)d_in[2];
    const float* D_W1    = (const float*)d_in[3];
    const float* PP_W1   = (const float*)d_in[4];
    const float* b1_init = (const float*)d_in[5];
    const float* D_b1    = (const float*)d_in[6];
    const float* PP_b1   = (const float*)d_in[7];
    const float* W2_init = (const float*)d_in[8];
    const float* D_W2    = (const float*)d_in[9];
    const float* PP_W2   = (const float*)d_in[10];
    const float* b2_init = (const float*)d_in[11];
    const float* D_b2    = (const float*)d_in[12];
    const float* PP_b2   = (const float*)d_in[13];

    constexpr size_t MB = 1024 * 1024;
    char* ws = (char*)d_ws;
    float* g    = (float*)(ws);                      // 4x1024 f32: [W1 | b1 | W2 | b2]
    float* b1w  = (float*)(ws + 16384);              // 4096 f32
    float* b2w  = (float*)(ws + 32768);              // 4096 f32
    u16*   xb   = (u16*)(ws + 65536);                // 512x4096 bf16 (4 MB)
    u16*   hb   = (u16*)(ws + 65536 + 4 * MB);       // 512x4096 bf16 (4 MB)
    float* Pbuf = (float*)(ws + 65536 + 8 * MB);     // 4x512x4096 f32 (32 MB)

    const int M = 512, N = 4096, K = 4096, S = 4, Kslice = K / S;

    fwht_g_kernel<<<4, 1024, 0, stream>>>(V, D_W1, D_b1, D_W2, D_b2, g);
    bias_kernel<<<4, 1024, 0, stream>>>(b1_init, PP_b1, g + 1024, b1w, 4096);
    bias_kernel<<<4, 1024, 0, stream>>>(b2_init, PP_b2, g + 3072, b2w, 4096);
    cast_kernel<<<2048, 256, 0, stream>>>(x, xb, M * K / 4);

    // layer 1: fused W1-gen GEMM
    gemm_fused<<<dim3(N / 64, M / 256, S), 256, 0, stream>>>(xb, W1_init, PP_W1, g, Pbuf, M, N, K, Kslice);
    reduce_kernel<u16, true, S><<<M * N / 4 / 256, 256, 0, stream>>>(Pbuf, b1w, hb, M * N, N);

    // layer 2: fused W2-gen GEMM
    gemm_fused<<<dim3(N / 64, M / 256, S), 256, 0, stream>>>(hb, W2_init, PP_W2, g + 2048, Pbuf, M, N, K, Kslice);
    reduce_kernel<float, false, S><<<M * N / 4 / 256, 256, 0, stream>>>(Pbuf, b2w, (float*)d_out, M * N, N);
}

// Round 7
// 144.174 us; speedup vs baseline: 2.0082x; 1.0030x over previous
//
#include <hip/hip_runtime.h>
#include <hip/hip_bf16.h>
#include <stdint.h>

typedef unsigned short u16;
typedef __attribute__((ext_vector_type(8))) short short8;
typedef __attribute__((ext_vector_type(4))) float f32x4;

// ---------- helpers ----------
__device__ __forceinline__ uint32_t f2bf(float f) {
    union { float f; uint32_t u; } c; c.f = f;
    uint32_t u = c.u;
    u += 0x7fffu + ((u >> 16) & 1u);   // round-to-nearest-even
    return u >> 16;
}

__device__ __forceinline__ void glds16(const void* g, void* l) {
    __builtin_amdgcn_global_load_lds(
        (const __attribute__((address_space(1))) uint32_t*)g,
        (__attribute__((address_space(3))) uint32_t*)l,
        16, 0, 0);
}

__device__ __forceinline__ uint2 wrow2(float4 wi, float4 pp, float4 gv) {
    uint32_t lo = f2bf(wi.x + pp.x * gv.x) | (f2bf(wi.y + pp.y * gv.y) << 16);
    uint32_t hi = f2bf(wi.z + pp.z * gv.z) | (f2bf(wi.w + pp.w * gv.w) << 16);
    return make_uint2(lo, hi);
}

// ---------- kernel 1: g_p = FWHT_1024(D_p[:1024] * V) / 1024, for 4 params ----------
__global__ void fwht_g_kernel(const float* __restrict__ V,
                              const float* __restrict__ D0, const float* __restrict__ D1,
                              const float* __restrict__ D2, const float* __restrict__ D3,
                              float* __restrict__ g) {
    __shared__ float s[1024];
    int t = threadIdx.x;
    const float* D = (blockIdx.x == 0) ? D0 : (blockIdx.x == 1) ? D1 :
                     (blockIdx.x == 2) ? D2 : D3;
    s[t] = D[t] * V[t];
    __syncthreads();
    #pragma unroll
    for (int st = 512; st >= 1; st >>= 1) {
        float a = s[t];
        float b = s[t ^ st];
        __syncthreads();
        s[t] = (t & st) ? (b - a) : (a + b);
        __syncthreads();
    }
    g[blockIdx.x * 1024 + t] = s[t] * (1.0f / 1024.0f);
}

// ---------- kernel 2: bias = init + PP * g[i&1023] ----------
__global__ void bias_kernel(const float* __restrict__ init, const float* __restrict__ PP,
                            const float* __restrict__ g, float* __restrict__ out, int n) {
    int i = blockIdx.x * blockDim.x + threadIdx.x;
    if (i < n) out[i] = init[i] + PP[i] * g[i & 1023];
}

// ---------- kernel 3: f32 -> bf16 cast (x), 4 elems/thread ----------
__global__ void cast_kernel(const float* __restrict__ in, u16* __restrict__ out, int n4) {
    int i = blockIdx.x * blockDim.x + threadIdx.x;
    if (i >= n4) return;
    float4 v = ((const float4*)in)[i];
    uint32_t lo = f2bf(v.x) | (f2bf(v.y) << 16);
    uint32_t hi = f2bf(v.z) | (f2bf(v.w) << 16);
    ((uint2*)out)[i] = make_uint2(lo, hi);
}

// ---------- kernel 4: fused W-gen + split-K GEMM, v4 (single-barrier pipeline) ----------
// P[sk] = A(256-row slice x Ks) @ W^T, W[n][k] = bf16(Winit + PP * g[k&1023]).
// Full double-buffer (As/Bs x2), W prefetched 2 K-steps ahead into two NAMED
// register sets, ONE __syncthreads per K-step. BM=256, BN=64, BK=64; 4 waves
// stacked in M; wave tile 64x64, acc[4][4] (32 MFMA/wave/step).
__global__ __launch_bounds__(256, 2) void gemm_fused(const u16* __restrict__ A,
                                                     const float* __restrict__ Winit,
                                                     const float* __restrict__ PP,
                                                     const float* __restrict__ gvec,
                                                     float* __restrict__ P,
                                                     int M, int N, int K, int Kslice) {
    constexpr int BM = 256, BN = 64, BK = 64;
    __shared__ u16 As[2][BM * BK];   // 2 x 32 KB
    __shared__ u16 Bs[2][BN * BK];   // 2 x 8 KB   -> 80 KB total, 2 WG/CU

    const int t    = threadIdx.x;
    const int wid  = t >> 6;          // 0..3, owns 64 A-rows
    const int lane = t & 63;
    const int fr   = lane & 15;
    const int fq   = lane >> 4;

    const int bn = blockIdx.x, bm = blockIdx.y, sk = blockIdx.z;
    const int k_beg = sk * Kslice;
    const int npair = (Kslice / BK) / 2;   // 8 pairs of K-steps

    const u16* Abase = A + (size_t)(bm * BM) * K;

    // B-gen mapping: thread covers W rows rB+{0,16,32,48}, k-cols cB..cB+3
    const int rB = t >> 4;            // 0..15
    const int cB = (t & 15) * 4;      // 0..60
    const float* Wb = Winit + (size_t)(bn * BN + rB) * K;
    const float* Pb = PP    + (size_t)(bn * BN + rB) * K;
    const size_t rstride = (size_t)16 * K;

    // two named W-register sets (set0 feeds even steps' B, set1 odd steps')
    float4 w00, w01, w02, w03, p00, p01, p02, p03;
    float4 w10, w11, w12, w13, p10, p11, p12, p13;

#define PF_W0(k0) do {                                        \
        const float* wp_ = Wb + (k0) + cB;                    \
        const float* qp_ = Pb + (k0) + cB;                    \
        w00 = *(const float4*)(wp_);                          \
        w01 = *(const float4*)(wp_ + rstride);                \
        w02 = *(const float4*)(wp_ + 2 * rstride);            \
        w03 = *(const float4*)(wp_ + 3 * rstride);            \
        p00 = *(const float4*)(qp_);                          \
        p01 = *(const float4*)(qp_ + rstride);                \
        p02 = *(const float4*)(qp_ + 2 * rstride);            \
        p03 = *(const float4*)(qp_ + 3 * rstride);            \
    } while (0)

#define PF_W1(k0) do {                                        \
        const float* wp_ = Wb + (k0) + cB;                    \
        const float* qp_ = Pb + (k0) + cB;                    \
        w10 = *(const float4*)(wp_);                          \
        w11 = *(const float4*)(wp_ + rstride);                \
        w12 = *(const float4*)(wp_ + 2 * rstride);            \
        w13 = *(const float4*)(wp_ + 3 * rstride);            \
        p10 = *(const float4*)(qp_);                          \
        p11 = *(const float4*)(qp_ + rstride);                \
        p12 = *(const float4*)(qp_ + 2 * rstride);            \
        p13 = *(const float4*)(qp_ + 3 * rstride);            \
    } while (0)

#define WRITE_B0(k0, buf) do {                                                    \
        float4 gv_ = *(const float4*)(gvec + (((k0) + cB) & 1023));               \
        *(uint2*)(Bs[buf] + (rB +  0) * BK + cB) = wrow2(w00, p00, gv_);          \
        *(uint2*)(Bs[buf] + (rB + 16) * BK + cB) = wrow2(w01, p01, gv_);          \
        *(uint2*)(Bs[buf] + (rB + 32) * BK + cB) = wrow2(w02, p02, gv_);          \
        *(uint2*)(Bs[buf] + (rB + 48) * BK + cB) = wrow2(w03, p03, gv_);          \
    } while (0)

#define WRITE_B1(k0, buf) do {                                                    \
        float4 gv_ = *(const float4*)(gvec + (((k0) + cB) & 1023));               \
        *(uint2*)(Bs[buf] + (rB +  0) * BK + cB) = wrow2(w10, p10, gv_);          \
        *(uint2*)(Bs[buf] + (rB + 16) * BK + cB) = wrow2(w11, p11, gv_);          \
        *(uint2*)(Bs[buf] + (rB + 32) * BK + cB) = wrow2(w12, p12, gv_);          \
        *(uint2*)(Bs[buf] + (rB + 48) * BK + cB) = wrow2(w13, p13, gv_);          \
    } while (0)

#define STAGE_A(k0, buf) do {                                                     \
        _Pragma("unroll")                                                         \
        for (int q_ = 0; q_ < 8; ++q_) {                                          \
            int L_ = q_ * 256 + t;                                                \
            int row_ = L_ >> 3;                                                   \
            int cg_ = (L_ & 7) * 8;                                               \
            glds16(Abase + (size_t)row_ * K + (k0) + cg_, As[buf] + L_ * 8);      \
        }                                                                         \
    } while (0)

#define MFMA_STEP(buf) do {                                                       \
        __builtin_amdgcn_s_setprio(1);                                            \
        _Pragma("unroll")                                                         \
        for (int ks_ = 0; ks_ < 2; ++ks_) {                                       \
            short8 a_[4], b_[4];                                                  \
            _Pragma("unroll")                                                     \
            for (int m_ = 0; m_ < 4; ++m_)                                        \
                a_[m_] = *(const short8*)(As[buf] +                               \
                          (wid * 64 + m_ * 16 + fr) * BK + ks_ * 32 + fq * 8);    \
            _Pragma("unroll")                                                     \
            for (int n_ = 0; n_ < 4; ++n_)                                        \
                b_[n_] = *(const short8*)(Bs[buf] +                               \
                          (n_ * 16 + fr) * BK + ks_ * 32 + fq * 8);               \
            _Pragma("unroll")                                                     \
            for (int m_ = 0; m_ < 4; ++m_)                                        \
                _Pragma("unroll")                                                 \
                for (int n_ = 0; n_ < 4; ++n_)                                    \
                    acc[m_][n_] = __builtin_amdgcn_mfma_f32_16x16x32_bf16(        \
                        a_[m_], b_[n_], acc[m_][n_], 0, 0, 0);                    \
        }                                                                         \
        __builtin_amdgcn_s_setprio(0);                                            \
    } while (0)

    f32x4 acc[4][4];
    #pragma unroll
    for (int m = 0; m < 4; ++m)
        #pragma unroll
        for (int n = 0; n < 4; ++n)
            acc[m][n] = (f32x4){0.f, 0.f, 0.f, 0.f};

    // ---- prologue: W for steps 0,1 in flight; tile 0 staged ----
    PF_W0(k_beg);                 // W(0) -> set0
    PF_W1(k_beg + BK);            // W(1) -> set1
    STAGE_A(k_beg, 0);            // A(0) -> As0
    WRITE_B0(k_beg, 0);           // B(0) from set0 -> Bs0
    __syncthreads();

    // ---- main loop: pairs of K-steps, one barrier per step ----
    int kk = k_beg;
    #pragma unroll 1
    for (int p = 0; p < npair - 1; ++p, kk += 2 * BK) {
        // even step s: compute (As0,Bs0); prep step s+1; W for s+2
        PF_W0(kk + 2 * BK);           // W(s+2) -> set0
        STAGE_A(kk + BK, 1);          // A(s+1) -> As1
        WRITE_B1(kk + BK, 1);         // B(s+1) from set1 (issued one step ago)
        MFMA_STEP(0);
        __syncthreads();
        // odd step s+1: compute (As1,Bs1); prep step s+2; W for s+3
        PF_W1(kk + 3 * BK);           // W(s+3) -> set1
        STAGE_A(kk + 2 * BK, 0);      // A(s+2) -> As0
        WRITE_B0(kk + 2 * BK, 0);     // B(s+2) from set0
        MFMA_STEP(1);
        __syncthreads();
    }
    // ---- tail pair (no prefetch past end) ----
    STAGE_A(kk + BK, 1);
    WRITE_B1(kk + BK, 1);
    MFMA_STEP(0);
    __syncthreads();
    MFMA_STEP(1);

#undef PF_W0
#undef PF_W1
#undef WRITE_B0
#undef WRITE_B1
#undef STAGE_A
#undef MFMA_STEP

    // epilogue: write f32 partial tile
    float* Pp = P + (size_t)sk * M * N;
    #pragma unroll
    for (int m = 0; m < 4; ++m) {
        int grow0 = bm * BM + wid * 64 + m * 16 + fq * 4;
        #pragma unroll
        for (int n = 0; n < 4; ++n) {
            int gcol = bn * BN + n * 16 + fr;
            #pragma unroll
            for (int j = 0; j < 4; ++j)
                Pp[(size_t)(grow0 + j) * N + gcol] = acc[m][n][j];
        }
    }
}

// ---------- kernel 5: reduce S partials + bias (+relu) -> bf16 or f32 ----------
template <typename OutT, bool RELU, int S>
__global__ void reduce_kernel(const float* __restrict__ P, const float* __restrict__ bias,
                              OutT* __restrict__ out, int MN, int N) {
    int i = blockIdx.x * blockDim.x + threadIdx.x;   // handles 4 elems
    if (i * 4 >= MN) return;
    int e = i * 4;
    int col = e & (N - 1);
    float4 acc = ((const float4*)(P + e))[0];
    #pragma unroll
    for (int s = 1; s < S; ++s) {
        float4 p = ((const float4*)(P + (size_t)s * MN + e))[0];
        acc.x += p.x; acc.y += p.y; acc.z += p.z; acc.w += p.w;
    }
    float4 bv = *((const float4*)(bias + col));
    acc.x += bv.x; acc.y += bv.y; acc.z += bv.z; acc.w += bv.w;
    if (RELU) {
        acc.x = fmaxf(acc.x, 0.f); acc.y = fmaxf(acc.y, 0.f);
        acc.z = fmaxf(acc.z, 0.f); acc.w = fmaxf(acc.w, 0.f);
    }
    if constexpr (sizeof(OutT) == 2) {
        uint32_t lo = f2bf(acc.x) | (f2bf(acc.y) << 16);
        uint32_t hi = f2bf(acc.z) | (f2bf(acc.w) << 16);
        ((uint2*)out)[i] = make_uint2(lo, hi);
    } else {
        ((float4*)out)[i] = acc;
    }
}

// ---------- launch ----------
extern "C" void kernel_launch(void* const* d_in, const int* in_sizes, int n_in,
                              void* d_out, int out_size, void* d_ws, size_t ws_size,
                              hipStream_t stream) {
    (void)in_sizes; (void)n_in; (void)out_size; (void)ws_size;

    const float* x       = (const float*)d_in[0];
    const float* V       = (const float*)d_in[1];
    const float* W1_init = (const float*)d_in[2];
    const float* D_W1    = (const float*)d_in[3];
    const float* PP_W1   = (const float*)d_in[4];
    const float* b1_init = (const float*)d_in[5];
    const float* D_b1    = (const float*)d_in[6];
    const float* PP_b1   = (const float*)d_in[7];
    const float* W2_init = (const float*)d_in[8];
    const float* D_W2    = (const float*)d_in[9];
    const float* PP_W2   = (const float*)d_in[10];
    const float* b2_init = (const float*)d_in[11];
    const float* D_b2    = (const float*)d_in[12];
    const float* PP_b2   = (const float*)d_in[13];

    constexpr size_t MB = 1024 * 1024;
    char* ws = (char*)d_ws;
    float* g    = (float*)(ws);                      // 4x1024 f32: [W1 | b1 | W2 | b2]
    float* b1w  = (float*)(ws + 16384);              // 4096 f32
    float* b2w  = (float*)(ws + 32768);              // 4096 f32
    u16*   xb   = (u16*)(ws + 65536);                // 512x4096 bf16 (4 MB)
    u16*   hb   = (u16*)(ws + 65536 + 4 * MB);       // 512x4096 bf16 (4 MB)
    float* Pbuf = (float*)(ws + 65536 + 8 * MB);     // 4x512x4096 f32 (32 MB)

    const int M = 512, N = 4096, K = 4096, S = 4, Kslice = K / S;

    fwht_g_kernel<<<4, 1024, 0, stream>>>(V, D_W1, D_b1, D_W2, D_b2, g);
    bias_kernel<<<4, 1024, 0, stream>>>(b1_init, PP_b1, g + 1024, b1w, 4096);
    bias_kernel<<<4, 1024, 0, stream>>>(b2_init, PP_b2, g + 3072, b2w, 4096);
    cast_kernel<<<2048, 256, 0, stream>>>(x, xb, M * K / 4);

    // layer 1: fused W1-gen GEMM
    gemm_fused<<<dim3(N / 64, M / 256, S), 256, 0, stream>>>(xb, W1_init, PP_W1, g, Pbuf, M, N, K, Kslice);
    reduce_kernel<u16, true, S><<<M * N / 4 / 256, 256, 0, stream>>>(Pbuf, b1w, hb, M * N, N);

    // layer 2: fused W2-gen GEMM
    gemm_fused<<<dim3(N / 64, M / 256, S), 256, 0, stream>>>(hb, W2_init, PP_W2, g + 2048, Pbuf, M, N, K, Kslice);
    reduce_kernel<float, false, S><<<M * N / 4 / 256, 256, 0, stream>>>(Pbuf, b2w, (float*)d_out, M * N, N);
}

// Round 8
// 130.130 us; speedup vs baseline: 2.2249x; 1.1079x over previous
//
#include <hip/hip_runtime.h>
#include <hip/hip_bf16.h>
#include <stdint.h>

typedef unsigned short u16;
typedef __attribute__((ext_vector_type(8))) short short8;
typedef __attribute__((ext_vector_type(4))) float f32x4;

// ---------- helpers ----------
__device__ __forceinline__ uint32_t f2bf(float f) {
    union { float f; uint32_t u; } c; c.f = f;
    uint32_t u = c.u;
    u += 0x7fffu + ((u >> 16) & 1u);   // round-to-nearest-even
    return u >> 16;
}

__device__ __forceinline__ void glds16(const void* g, void* l) {
    __builtin_amdgcn_global_load_lds(
        (const __attribute__((address_space(1))) uint32_t*)g,
        (__attribute__((address_space(3))) uint32_t*)l,
        16, 0, 0);
}

__device__ __forceinline__ uint2 wrow2(float4 wi, float4 pp, float4 gv) {
    uint32_t lo = f2bf(wi.x + pp.x * gv.x) | (f2bf(wi.y + pp.y * gv.y) << 16);
    uint32_t hi = f2bf(wi.z + pp.z * gv.z) | (f2bf(wi.w + pp.w * gv.w) << 16);
    return make_uint2(lo, hi);
}

// ---------- kernel 1: g_p = FWHT_1024(D_p[:1024] * V) / 1024, for 4 params ----------
__global__ void fwht_g_kernel(const float* __restrict__ V,
                              const float* __restrict__ D0, const float* __restrict__ D1,
                              const float* __restrict__ D2, const float* __restrict__ D3,
                              float* __restrict__ g) {
    __shared__ float s[1024];
    int t = threadIdx.x;
    const float* D = (blockIdx.x == 0) ? D0 : (blockIdx.x == 1) ? D1 :
                     (blockIdx.x == 2) ? D2 : D3;
    s[t] = D[t] * V[t];
    __syncthreads();
    #pragma unroll
    for (int st = 512; st >= 1; st >>= 1) {
        float a = s[t];
        float b = s[t ^ st];
        __syncthreads();
        s[t] = (t & st) ? (b - a) : (a + b);
        __syncthreads();
    }
    g[blockIdx.x * 1024 + t] = s[t] * (1.0f / 1024.0f);
}

// ---------- kernel 2: bias = init + PP * g[i&1023] ----------
__global__ void bias_kernel(const float* __restrict__ init, const float* __restrict__ PP,
                            const float* __restrict__ g, float* __restrict__ out, int n) {
    int i = blockIdx.x * blockDim.x + threadIdx.x;
    if (i < n) out[i] = init[i] + PP[i] * g[i & 1023];
}

// ---------- kernel 3: f32 -> bf16 cast (x), 4 elems/thread ----------
__global__ void cast_kernel(const float* __restrict__ in, u16* __restrict__ out, int n4) {
    int i = blockIdx.x * blockDim.x + threadIdx.x;
    if (i >= n4) return;
    float4 v = ((const float4*)in)[i];
    uint32_t lo = f2bf(v.x) | (f2bf(v.y) << 16);
    uint32_t hi = f2bf(v.z) | (f2bf(v.w) << 16);
    ((uint2*)out)[i] = make_uint2(lo, hi);
}

// ---------- kernel 4: fused W-gen + split-K GEMM, v5 ----------
// Counted-vmcnt raw barrier (T4) + LDS XOR swizzle (T2, both-sides: pre-swizzled
// glds source for As, swizzled ds_write for Bs). Double-buffered LDS, W inputs
// prefetched 2 steps ahead in named regs. One barrier per K-step; per wave per
// step: 8 glds (oldest) + 8 W-loads (stay in flight across barrier, vmcnt(8)).
__global__ __launch_bounds__(256, 2) void gemm_fused(const u16* __restrict__ A,
                                                     const float* __restrict__ Winit,
                                                     const float* __restrict__ PP,
                                                     const float* __restrict__ gvec,
                                                     float* __restrict__ P,
                                                     int M, int N, int K, int Kslice) {
    constexpr int BM = 256, BN = 64, BK = 64;
    __shared__ u16 As[2][BM * BK];   // 2 x 32 KB
    __shared__ u16 Bs[2][BN * BK];   // 2 x 8 KB   -> 80 KB, 2 WG/CU

    const int t    = threadIdx.x;
    const int wid  = t >> 6;          // 0..3, owns 64 A-rows
    const int lane = t & 63;
    const int fr   = lane & 15;
    const int fq   = lane >> 4;
    const int rx   = (fr & 7) << 4;   // read-side swizzle xor (bytes)

    const int bn = blockIdx.x, bm = blockIdx.y, sk = blockIdx.z;
    const int k_beg = sk * Kslice;
    const int kmax  = k_beg + Kslice - BK;
    const int npair = (Kslice / BK) / 2;

    const u16* Abase = A + (size_t)(bm * BM) * K;

    // B-gen mapping: thread covers W rows rB+{0,16,32,48}, k-cols cB..cB+3
    const int rB  = t >> 4;           // 0..15
    const int cB  = (t & 15) * 4;     // 0..60 (f32 elems)
    const int cb8 = (t & 15) * 8;     // byte col in Bs row
    const int wxor = (rB & 7) << 4;   // write-side swizzle xor (bytes)
    const float* Wb = Winit + (size_t)(bn * BN + rB) * K;
    const float* Pb = PP    + (size_t)(bn * BN + rB) * K;
    const size_t rstride = (size_t)16 * K;

    float4 w00, w01, w02, w03, p00, p01, p02, p03;   // W set0 (even steps' B)
    float4 w10, w11, w12, w13, p10, p11, p12, p13;   // W set1 (odd steps' B)

#define PF_W0(k0) do {                                        \
        const float* wp_ = Wb + (k0) + cB;                    \
        const float* qp_ = Pb + (k0) + cB;                    \
        w00 = *(const float4*)(wp_);                          \
        w01 = *(const float4*)(wp_ + rstride);                \
        w02 = *(const float4*)(wp_ + 2 * rstride);            \
        w03 = *(const float4*)(wp_ + 3 * rstride);            \
        p00 = *(const float4*)(qp_);                          \
        p01 = *(const float4*)(qp_ + rstride);                \
        p02 = *(const float4*)(qp_ + 2 * rstride);            \
        p03 = *(const float4*)(qp_ + 3 * rstride);            \
    } while (0)

#define PF_W1(k0) do {                                        \
        const float* wp_ = Wb + (k0) + cB;                    \
        const float* qp_ = Pb + (k0) + cB;                    \
        w10 = *(const float4*)(wp_);                          \
        w11 = *(const float4*)(wp_ + rstride);                \
        w12 = *(const float4*)(wp_ + 2 * rstride);            \
        w13 = *(const float4*)(wp_ + 3 * rstride);            \
        p10 = *(const float4*)(qp_);                          \
        p11 = *(const float4*)(qp_ + rstride);                \
        p12 = *(const float4*)(qp_ + 2 * rstride);            \
        p13 = *(const float4*)(qp_ + 3 * rstride);            \
    } while (0)

// swizzled B write: logical byte (row*128 + cb8) ^ ((row&7)<<4); (row&7)==(rB&7)
#define WRITE_B0(k0, buf) do {                                                    \
        float4 gv_ = *(const float4*)(gvec + (((k0) + cB) & 1023));               \
        char* Bp_ = (char*)Bs[buf];                                               \
        *(uint2*)(Bp_ + ((((rB +  0) * 128 + cb8)) ^ wxor)) = wrow2(w00, p00, gv_); \
        *(uint2*)(Bp_ + ((((rB + 16) * 128 + cb8)) ^ wxor)) = wrow2(w01, p01, gv_); \
        *(uint2*)(Bp_ + ((((rB + 32) * 128 + cb8)) ^ wxor)) = wrow2(w02, p02, gv_); \
        *(uint2*)(Bp_ + ((((rB + 48) * 128 + cb8)) ^ wxor)) = wrow2(w03, p03, gv_); \
    } while (0)

#define WRITE_B1(k0, buf) do {                                                    \
        float4 gv_ = *(const float4*)(gvec + (((k0) + cB) & 1023));               \
        char* Bp_ = (char*)Bs[buf];                                               \
        *(uint2*)(Bp_ + ((((rB +  0) * 128 + cb8)) ^ wxor)) = wrow2(w10, p10, gv_); \
        *(uint2*)(Bp_ + ((((rB + 16) * 128 + cb8)) ^ wxor)) = wrow2(w11, p11, gv_); \
        *(uint2*)(Bp_ + ((((rB + 32) * 128 + cb8)) ^ wxor)) = wrow2(w12, p12, gv_); \
        *(uint2*)(Bp_ + ((((rB + 48) * 128 + cb8)) ^ wxor)) = wrow2(w13, p13, gv_); \
    } while (0)

// As staging: LDS dest linear (glds requirement); SOURCE col-group pre-swizzled
#define STAGE_A(k0, buf) do {                                                     \
        _Pragma("unroll")                                                         \
        for (int q_ = 0; q_ < 8; ++q_) {                                          \
            int L_ = q_ * 256 + t;                 /* 16B chunk index */          \
            int row_ = L_ >> 3;                                                   \
            int cg_ = (L_ & 7) ^ (row_ & 7);       /* swizzled src col16 */       \
            glds16(Abase + (size_t)row_ * K + (k0) + cg_ * 8, As[buf] + L_ * 8);  \
        }                                                                         \
    } while (0)

#define MFMA_STEP(buf) do {                                                       \
        const char* Ap_ = (const char*)As[buf];                                   \
        const char* Bp_ = (const char*)Bs[buf];                                   \
        __builtin_amdgcn_s_setprio(1);                                            \
        _Pragma("unroll")                                                         \
        for (int ks_ = 0; ks_ < 2; ++ks_) {                                       \
            const int co_ = (ks_ * 64 + fq * 16) ^ rx;                            \
            short8 a_[4], b_[4];                                                  \
            _Pragma("unroll")                                                     \
            for (int m_ = 0; m_ < 4; ++m_)                                        \
                a_[m_] = *(const short8*)(Ap_ +                                   \
                          (wid * 64 + m_ * 16 + fr) * 128 + co_);                 \
            _Pragma("unroll")                                                     \
            for (int n_ = 0; n_ < 4; ++n_)                                        \
                b_[n_] = *(const short8*)(Bp_ + (n_ * 16 + fr) * 128 + co_);      \
            _Pragma("unroll")                                                     \
            for (int m_ = 0; m_ < 4; ++m_)                                        \
                _Pragma("unroll")                                                 \
                for (int n_ = 0; n_ < 4; ++n_)                                    \
                    acc[m_][n_] = __builtin_amdgcn_mfma_f32_16x16x32_bf16(        \
                        a_[m_], b_[n_], acc[m_][n_], 0, 0, 0);                    \
        }                                                                         \
        __builtin_amdgcn_s_setprio(0);                                            \
    } while (0)

// counted barrier: drain the 8 glds (oldest), keep 8 W-loads in flight
#define WAIT_BAR() do {                                                           \
        asm volatile("s_waitcnt vmcnt(8) lgkmcnt(0)" ::: "memory");               \
        __builtin_amdgcn_s_barrier();                                             \
        __builtin_amdgcn_sched_barrier(0);                                        \
    } while (0)

    f32x4 acc[4][4];
    #pragma unroll
    for (int m = 0; m < 4; ++m)
        #pragma unroll
        for (int n = 0; n < 4; ++n)
            acc[m][n] = (f32x4){0.f, 0.f, 0.f, 0.f};

    // ---- prologue: issue order = W0(8), glds(8), W1(8) ----
    PF_W0(k_beg);
    __builtin_amdgcn_sched_barrier(0);
    STAGE_A(k_beg, 0);
    __builtin_amdgcn_sched_barrier(0);
    PF_W1(k_beg + BK);
    __builtin_amdgcn_sched_barrier(0);
    WRITE_B0(k_beg, 0);                 // auto-waits set0 (vmcnt(16))
    WAIT_BAR();                          // glds(0) done; W1 stays in flight

    // ---- main loop: 1 barrier per K-step; W pipeline depth 2 ----
    int kk = k_beg;
    #pragma unroll 1
    for (int p = 0; p < npair; ++p, kk += 2 * BK) {
        const int nk = kk + BK;
        int n2 = kk + 2 * BK; if (n2 > kmax) n2 = kmax;   // clamped dummy at tail
        int n3 = kk + 3 * BK; if (n3 > kmax) n3 = kmax;

        // even step (buf0): stage s+1, prefetch W(s+2), compute s
        STAGE_A(nk, 1);
        __builtin_amdgcn_sched_barrier(0);
        PF_W0(n2);
        __builtin_amdgcn_sched_barrier(0);
        MFMA_STEP(0);
        WRITE_B1(nk, 1);                 // uses set1 (1 step old), auto vmcnt(16)
        WAIT_BAR();

        // odd step (buf1): stage s+2, prefetch W(s+3), compute s+1
        STAGE_A(n2, 0);
        __builtin_amdgcn_sched_barrier(0);
        PF_W1(n3);
        __builtin_amdgcn_sched_barrier(0);
        MFMA_STEP(1);
        WRITE_B0(n2, 0);                 // uses set0, auto vmcnt(16)
        WAIT_BAR();
    }

#undef PF_W0
#undef PF_W1
#undef WRITE_B0
#undef WRITE_B1
#undef STAGE_A
#undef MFMA_STEP
#undef WAIT_BAR

    // epilogue: write f32 partial tile
    float* Pp = P + (size_t)sk * M * N;
    #pragma unroll
    for (int m = 0; m < 4; ++m) {
        int grow0 = bm * BM + wid * 64 + m * 16 + fq * 4;
        #pragma unroll
        for (int n = 0; n < 4; ++n) {
            int gcol = bn * BN + n * 16 + fr;
            #pragma unroll
            for (int j = 0; j < 4; ++j)
                Pp[(size_t)(grow0 + j) * N + gcol] = acc[m][n][j];
        }
    }
}

// ---------- kernel 5: reduce S partials + bias (+relu) -> bf16 or f32 ----------
template <typename OutT, bool RELU, int S>
__global__ void reduce_kernel(const float* __restrict__ P, const float* __restrict__ bias,
                              OutT* __restrict__ out, int MN, int N) {
    int i = blockIdx.x * blockDim.x + threadIdx.x;   // handles 4 elems
    if (i * 4 >= MN) return;
    int e = i * 4;
    int col = e & (N - 1);
    float4 acc = ((const float4*)(P + e))[0];
    #pragma unroll
    for (int s = 1; s < S; ++s) {
        float4 p = ((const float4*)(P + (size_t)s * MN + e))[0];
        acc.x += p.x; acc.y += p.y; acc.z += p.z; acc.w += p.w;
    }
    float4 bv = *((const float4*)(bias + col));
    acc.x += bv.x; acc.y += bv.y; acc.z += bv.z; acc.w += bv.w;
    if (RELU) {
        acc.x = fmaxf(acc.x, 0.f); acc.y = fmaxf(acc.y, 0.f);
        acc.z = fmaxf(acc.z, 0.f); acc.w = fmaxf(acc.w, 0.f);
    }
    if constexpr (sizeof(OutT) == 2) {
        uint32_t lo = f2bf(acc.x) | (f2bf(acc.y) << 16);
        uint32_t hi = f2bf(acc.z) | (f2bf(acc.w) << 16);
        ((uint2*)out)[i] = make_uint2(lo, hi);
    } else {
        ((float4*)out)[i] = acc;
    }
}

// ---------- launch ----------
extern "C" void kernel_launch(void* const* d_in, const int* in_sizes, int n_in,
                              void* d_out, int out_size, void* d_ws, size_t ws_size,
                              hipStream_t stream) {
    (void)in_sizes; (void)n_in; (void)out_size; (void)ws_size;

    const float* x       = (const float*)d_in[0];
    const float* V       = (const float*)d_in[1];
    const float* W1_init = (const float*)d_in[2];
    const float* D_W1    = (const float*)d_in[3];
    const float* PP_W1   = (const float*)d_in[4];
    const float* b1_init = (const float*)d_in[5];
    const float* D_b1    = (const float*)d_in[6];
    const float* PP_b1   = (const float*)d_in[7];
    const float* W2_init = (const float*)d_in[8];
    const float* D_W2    = (const float*)d_in[9];
    const float* PP_W2   = (const float*)d_in[10];
    const float* b2_init = (const float*)d_in[11];
    const float* D_b2    = (const float*)d_in[12];
    const float* PP_b2   = (const float*)d_in[13];

    constexpr size_t MB = 1024 * 1024;
    char* ws = (char*)d_ws;
    float* g    = (float*)(ws);                      // 4x1024 f32: [W1 | b1 | W2 | b2]
    float* b1w  = (float*)(ws + 16384);              // 4096 f32
    float* b2w  = (float*)(ws + 32768);              // 4096 f32
    u16*   xb   = (u16*)(ws + 65536);                // 512x4096 bf16 (4 MB)
    u16*   hb   = (u16*)(ws + 65536 + 4 * MB);       // 512x4096 bf16 (4 MB)
    float* Pbuf = (float*)(ws + 65536 + 8 * MB);     // 4x512x4096 f32 (32 MB)

    const int M = 512, N = 4096, K = 4096, S = 4, Kslice = K / S;

    fwht_g_kernel<<<4, 1024, 0, stream>>>(V, D_W1, D_b1, D_W2, D_b2, g);
    bias_kernel<<<4, 1024, 0, stream>>>(b1_init, PP_b1, g + 1024, b1w, 4096);
    bias_kernel<<<4, 1024, 0, stream>>>(b2_init, PP_b2, g + 3072, b2w, 4096);
    cast_kernel<<<2048, 256, 0, stream>>>(x, xb, M * K / 4);

    // layer 1: fused W1-gen GEMM
    gemm_fused<<<dim3(N / 64, M / 256, S), 256, 0, stream>>>(xb, W1_init, PP_W1, g, Pbuf, M, N, K, Kslice);
    reduce_kernel<u16, true, S><<<M * N / 4 / 256, 256, 0, stream>>>(Pbuf, b1w, hb, M * N, N);

    // layer 2: fused W2-gen GEMM
    gemm_fused<<<dim3(N / 64, M / 256, S), 256, 0, stream>>>(hb, W2_init, PP_W2, g + 2048, Pbuf, M, N, K, Kslice);
    reduce_kernel<float, false, S><<<M * N / 4 / 256, 256, 0, stream>>>(Pbuf, b2w, (float*)d_out, M * N, N);
}